// Round 16
// baseline (187.524 us; speedup 1.0000x reference)
//
#include <hip/hip_runtime.h>
#include <hip/hip_bf16.h>
#include <hip/hip_fp16.h>
#include <math.h>

#define N_NODES 50000
#define N_EDGES 800000
#define HC      128     // HEADS*HID
#define OUTD    64
#define NBKT    ((N_NODES + 63) / 64)   // 782 buckets of 64 nodes

// fast exp2: single v_exp_f32
#if defined(__has_builtin)
#if __has_builtin(__builtin_amdgcn_exp2f)
#define EXP2(x) __builtin_amdgcn_exp2f(x)
#endif
#endif
#ifndef EXP2
#define EXP2(x) __expf((x) * 0.69314718055994531f)
#endif

typedef _Float16 f16x8 __attribute__((ext_vector_type(8)));
typedef float f32x4 __attribute__((ext_vector_type(4)));

// ---------------- bucketed CSR build + fused weight prep ----------------
// blocks [0, EB_NB): per-block LDS histogram of dst>>6.
// blocks [EB_NB, EB_NB+25): weight prep (independent work, saves a launch).

#define EB_NB ((N_EDGES + 8191) / 8192)   // 98

__global__ __launch_bounds__(1024) void k_hist_prep(
        const int* __restrict__ dst, int* __restrict__ bcnt, int e_cnt,
        const float* __restrict__ W0, const float* __restrict__ W1,
        const float* __restrict__ pW1, const float* __restrict__ pb1,
        const float* __restrict__ pW2, const float* __restrict__ pb2,
        __half* __restrict__ Wh0, __half* __restrict__ Wh1,
        __half* __restrict__ Wcht, float* __restrict__ bc) {
    if (blockIdx.x >= EB_NB) {
        int i = (blockIdx.x - EB_NB) * 1024 + threadIdx.x;
        if (i < HC * HC) {
            Wh0[i] = __float2half(W0[i]);
            Wh1[i] = __float2half(W1[i]);
        } else if (i < HC * HC + HC * OUTD) {
            int j = i - HC * HC;
            int k = j >> 6, o2 = j & 63;
            float s = 0.f;
            for (int m = 0; m < 64; ++m) s += pW2[o2 * 64 + m] * pW1[m * 128 + k];
            Wcht[o2 * 128 + k] = __float2half(s);   // [out][k] rows for MFMA B
        } else if (i < HC * HC + HC * OUTD + OUTD) {
            int o2 = i - HC * HC - HC * OUTD;
            float s = pb2[o2];
            for (int m = 0; m < 64; ++m) s += pW2[o2 * 64 + m] * pb1[m];
            bc[o2] = s;
        }
        return;
    }
    __shared__ int lh[NBKT];
    for (int i = threadIdx.x; i < NBKT; i += 1024) lh[i] = 0;
    __syncthreads();
    int base = blockIdx.x * 8192;
    for (int i = threadIdx.x; i < 8192; i += 1024) {
        int e = base + i;
        if (e < e_cnt) atomicAdd(&lh[dst[e] >> 6], 1);
    }
    __syncthreads();
    for (int i = threadIdx.x; i < NBKT; i += 1024) {
        int c = lh[i];
        if (c) atomicAdd(&bcnt[i], c);
    }
}

__global__ __launch_bounds__(1024) void k_bscan(const int* __restrict__ bcnt,
                                                int* __restrict__ bbase,
                                                int* __restrict__ bcur) {
    __shared__ int wsum[16];
    __shared__ int wexc[16];
    int t = threadIdx.x, lane = t & 63, wid = t >> 6;
    int v = (t < NBKT) ? bcnt[t] : 0;
    int incl = v;
    #pragma unroll
    for (int s = 1; s < 64; s <<= 1) {
        int u = __shfl_up(incl, s, 64);
        if (lane >= s) incl += u;
    }
    if (lane == 63) wsum[wid] = incl;
    __syncthreads();
    if (wid == 0 && lane < 16) {
        int w = wsum[lane];
        int wi = w;
        #pragma unroll
        for (int s = 1; s < 16; s <<= 1) {
            int u = __shfl_up(wi, s, 64);
            if (lane >= s) wi += u;
        }
        wexc[lane] = wi - w;
    }
    __syncthreads();
    int ex = wexc[wid] + incl - v;
    if (t < NBKT) { bbase[t] = ex; bcur[t] = ex; }
    if (t == NBKT - 1) bbase[NBKT] = ex + v;   // == e_cnt
}

__global__ __launch_bounds__(1024) void k_bscatter(const int* __restrict__ src,
                                                   const int* __restrict__ dst,
                                                   int* __restrict__ bcur,
                                                   uint2* __restrict__ ebuf, int e_cnt) {
    __shared__ int lcnt[NBKT];
    __shared__ int lbase[NBKT];
    for (int i = threadIdx.x; i < NBKT; i += 1024) lcnt[i] = 0;
    __syncthreads();
    int base = blockIdx.x * 8192;
    int myS[8], myD[8], myR[8];
    #pragma unroll
    for (int j = 0; j < 8; ++j) {
        int e = base + threadIdx.x + j * 1024;          // coalesced
        if (e < e_cnt) {
            myS[j] = src[e];
            myD[j] = dst[e];
            myR[j] = atomicAdd(&lcnt[myD[j] >> 6], 1);  // LDS rank (fast)
        } else myD[j] = -1;
    }
    __syncthreads();
    for (int i = threadIdx.x; i < NBKT; i += 1024) {
        int c = lcnt[i];
        lbase[i] = c ? atomicAdd(&bcur[i], c) : 0;      // reserve range once
    }
    __syncthreads();
    #pragma unroll
    for (int j = 0; j < 8; ++j) {
        if (myD[j] >= 0) {
            int bkt = myD[j] >> 6;
            ebuf[lbase[bkt] + myR[j]] =
                make_uint2((unsigned)myS[j], (unsigned)myD[j]);
        }
    }
}

__global__ __launch_bounds__(256) void k_bfinal(const uint2* __restrict__ ebuf,
                                                const int* __restrict__ bbase,
                                                int* __restrict__ off,
                                                int* __restrict__ esrc, int n) {
    __shared__ int ncnt[64];
    __shared__ int ncur[64];
    int b = blockIdx.x;
    int t = threadIdx.x;
    int ebeg = bbase[b], eend = bbase[b + 1];
    if (t < 64) ncnt[t] = 0;
    __syncthreads();
    for (int e = ebeg + t; e < eend; e += 256)
        atomicAdd(&ncnt[ebuf[e].y & 63], 1);
    __syncthreads();
    if (t < 64) {
        int v = ncnt[t];
        int incl = v;
        #pragma unroll
        for (int s = 1; s < 64; s <<= 1) {
            int u = __shfl_up(incl, s, 64);
            if (t >= s) incl += u;
        }
        int ex = incl - v;
        ncur[t] = ex;
        int node = b * 64 + t;
        if (node <= n) off[node] = ebeg + ex;   // covers off[n] via last bucket
    }
    __syncthreads();
    for (int e = ebeg + t; e < eend; e += 256) {
        uint2 ed = ebuf[e];
        int r = atomicAdd(&ncur[ed.y & 63], 1);
        esrc[ebeg + r] = (int)ed.x;             // contiguous 4KB region per block
    }
}

// ---------------- linear via MFMA: h = x @ W^T + b ----------------
// F16IN=false: x is fp32 (emb); F16IN=true: x is fp16 (xh from gat_agg) --
// staging is then a straight uint4 copy (no cvts, half the read traffic).

#define LSTR 136   // padded LDS row stride in fp16 elems

template <bool F16IN>
__global__ __launch_bounds__(256) void k_lin128(const void* __restrict__ xin,
                                                const __half* __restrict__ Wh,
                                                const float* __restrict__ bias,
                                                __half* __restrict__ h, int n) {
    __shared__ _Float16 wsh[128 * LSTR];   // 34.0KB: W fp16, padded rows
    __shared__ _Float16 xsh[32 * LSTR];    // 8.5KB: x fp16 (reused for output)
    int t = threadIdx.x;
    int node0 = blockIdx.x * 32;
    for (int i = t; i < 2048; i += 256) {
        int r = i >> 4, c16 = i & 15;
        *(uint4*)&wsh[r * LSTR + c16 * 8] = ((const uint4*)Wh)[i];
    }
    if (F16IN) {
        const uint4* xg = (const uint4*)xin;     // 16 uint4 per 128-fp16 row
        for (int i = t; i < 512; i += 256) {
            int r = i >> 4, c8 = i & 15;
            int gn = node0 + r;
            uint4 v = (gn < n) ? xg[(size_t)gn * 16 + c8]
                               : make_uint4(0u, 0u, 0u, 0u);
            *(uint4*)&xsh[r * LSTR + c8 * 8] = v;
        }
    } else {
        const float4* xg = (const float4*)xin;
        for (int i = t; i < 1024; i += 256) {
            int r = i >> 5, c4 = i & 31;
            int gn = node0 + r;
            float4 v = (gn < n) ? xg[(size_t)gn * 32 + c4]
                                : make_float4(0.f, 0.f, 0.f, 0.f);
            union { _Float16 hh[4]; uint2 u; } cv;
            cv.hh[0] = (_Float16)v.x; cv.hh[1] = (_Float16)v.y;
            cv.hh[2] = (_Float16)v.z; cv.hh[3] = (_Float16)v.w;
            *(uint2*)&xsh[r * LSTR + c4 * 4] = cv.u;
        }
    }
    __syncthreads();
    int w = t >> 6, l = t & 63;
    int lr = l & 15, lg = l >> 4;          // row-in-tile, k-group
    int nrow0 = (w >> 1) * 16;             // node tile base (0 / 16)
    int ccol0 = (w & 1) * 64;              // ch tile base (0 / 64)
    f32x4 acc0 = {0.f, 0.f, 0.f, 0.f};
    f32x4 acc1 = acc0, acc2 = acc0, acc3 = acc0;
    #pragma unroll
    for (int kk = 0; kk < 4; ++kk) {
        int ko = kk * 32 + lg * 8;
        f16x8 a  = *(const f16x8*)&xsh[(nrow0 + lr) * LSTR + ko];
        f16x8 b0 = *(const f16x8*)&wsh[(ccol0 +  0 + lr) * LSTR + ko];
        f16x8 b1 = *(const f16x8*)&wsh[(ccol0 + 16 + lr) * LSTR + ko];
        f16x8 b2 = *(const f16x8*)&wsh[(ccol0 + 32 + lr) * LSTR + ko];
        f16x8 b3 = *(const f16x8*)&wsh[(ccol0 + 48 + lr) * LSTR + ko];
        acc0 = __builtin_amdgcn_mfma_f32_16x16x32_f16(a, b0, acc0, 0, 0, 0);
        acc1 = __builtin_amdgcn_mfma_f32_16x16x32_f16(a, b1, acc1, 0, 0, 0);
        acc2 = __builtin_amdgcn_mfma_f32_16x16x32_f16(a, b2, acc2, 0, 0, 0);
        acc3 = __builtin_amdgcn_mfma_f32_16x16x32_f16(a, b3, acc3, 0, 0, 0);
    }
    float b0v = bias[ccol0 +  0 + lr];
    float b1v = bias[ccol0 + 16 + lr];
    float b2v = bias[ccol0 + 32 + lr];
    float b3v = bias[ccol0 + 48 + lr];
    __syncthreads();                       // all xsh reads done before overwrite
    int orow = nrow0 + lg * 4;
    #pragma unroll
    for (int j = 0; j < 4; ++j) {
        xsh[(orow + j) * LSTR + ccol0 +  0 + lr] = (_Float16)(acc0[j] + b0v);
        xsh[(orow + j) * LSTR + ccol0 + 16 + lr] = (_Float16)(acc1[j] + b1v);
        xsh[(orow + j) * LSTR + ccol0 + 32 + lr] = (_Float16)(acc2[j] + b2v);
        xsh[(orow + j) * LSTR + ccol0 + 48 + lr] = (_Float16)(acc3[j] + b3v);
    }
    __syncthreads();
    for (int i = t; i < 1024; i += 256) {
        int r = i >> 5, c4 = i & 31;
        int gn = node0 + r;
        if (gn < n)
            *(uint2*)&h[(size_t)gn * 128 + c4 * 4] = *(uint2*)&xsh[r * LSTR + c4 * 4];
    }
}

// ---------------- GAT aggregate (2-way parity, 47us verified) ----------------
// Round 16: output written as fp16 (numerically identical -- consumers
// previously rounded the fp32 value to fp16 in their own staging; the single
// round now just happens here). Halves the output write + downstream reads.

__global__ __launch_bounds__(256) void k_gat_agg(const __half* __restrict__ h,
                                                 const int* __restrict__ off,
                                                 const int* __restrict__ esrc,
                                                 const float* __restrict__ attl,
                                                 const float* __restrict__ attr,
                                                 __half* __restrict__ xout, int n,
                                                 float neg_out) {
    const float L2E = 1.4426950408889634f;
    int wid  = threadIdx.x >> 6;
    int lane = threadIdx.x & 63;
    int node = blockIdx.x * 4 + wid;
    if (node >= n) return;
    int half = lane >> 5;               // edge parity this half-wave owns
    int cq   = lane & 31;               // channel quad index
    uint32_t cq8 = (uint32_t)cq << 3;   // byte offset of my 4 fp16 channels

    const char* hb = (const char*)h;    // uniform base (SGPR) -- saddr form

    float4 alv = ((const float4*)attl)[cq];
    float4 arv = ((const float4*)attr)[cq];
    uint2 hdr = *(const uint2*)(hb + ((((uint32_t)node << 8)) | cq8));
    float2 hd01 = __half22float2(((const __half2*)&hdr)[0]);
    float2 hd23 = __half22float2(((const __half2*)&hdr)[1]);
    float al0 = alv.x * L2E, al1 = alv.y * L2E;
    float al2 = alv.z * L2E, al3 = alv.w * L2E;
    float ar0 = arv.x * hd01.x * L2E, ar1 = arv.y * hd01.y * L2E;
    float ar2 = arv.z * hd23.x * L2E, ar3 = arv.w * hd23.y * L2E;

    float z0 = 0.f, z1 = 0.f, z2 = 0.f, z3 = 0.f;
    float a0 = 0.f, a1 = 0.f, a2 = 0.f, a3 = 0.f;

    int beg = off[node], end = off[node + 1];

#define STEP(sAv)                                                              \
    {   uint32_t voff = (((uint32_t)(sAv)) << 8) | cq8;                        \
        uint2 hv = *(const uint2*)(hb + voff);                                 \
        float2 f01 = __half22float2(((const __half2*)&hv)[0]);                 \
        float2 f23 = __half22float2(((const __half2*)&hv)[1]);                 \
        float t0 = fmaf(al0, f01.x, ar0), t1 = fmaf(al1, f01.y, ar1);          \
        float t2 = fmaf(al2, f23.x, ar2), t3 = fmaf(al3, f23.y, ar3);          \
        float e0 = EXP2(fmaxf(t0, 0.2f * t0)), e1 = EXP2(fmaxf(t1, 0.2f * t1));\
        float e2 = EXP2(fmaxf(t2, 0.2f * t2)), e3 = EXP2(fmaxf(t3, 0.2f * t3));\
        z0 += e0; z1 += e1; z2 += e2; z3 += e3;                                \
        a0 = fmaf(e0, f01.x, a0); a1 = fmaf(e1, f01.y, a1);                    \
        a2 = fmaf(e2, f23.x, a2); a3 = fmaf(e3, f23.y, a3);                    \
    }

    {
        int e = beg;
        #pragma unroll 4
        for (; e + 2 <= end; e += 2) {
            int sA = esrc[e + half];    // half-wave-uniform -> L1 broadcast
            STEP(sA);
        }
        if (e < end) {                  // one leftover edge (even parity)
            int sA = esrc[end - 1];
            if (half == 0) STEP(sA);
        }
    }
#undef STEP

    // validity: overflow -> z inf/NaN; total underflow -> z==0 with edges
    float zs = z0 + z1 + z2 + z3;
    bool bad = !(zs < 3.0e38f);
    if (beg < end)
        bad = bad || !((z0 > 0.f) && (z1 > 0.f) && (z2 > 0.f) && (z3 > 0.f));

    if (__any(bad)) {
        // slow safe path (~never): two-pass max-shifted softmax; every lane
        // walks ALL edges, so both halves hold identical full sums (no merge).
        float m0 = -1e30f, m1 = -1e30f, m2 = -1e30f, m3 = -1e30f;
        for (int e = beg; e < end; ++e) {
            int sA = esrc[e];
            uint2 hv = *(const uint2*)(hb + (((uint32_t)sA << 8) | cq8));
            float2 f01 = __half22float2(((const __half2*)&hv)[0]);
            float2 f23 = __half22float2(((const __half2*)&hv)[1]);
            float t0 = fmaf(al0, f01.x, ar0), t1 = fmaf(al1, f01.y, ar1);
            float t2 = fmaf(al2, f23.x, ar2), t3 = fmaf(al3, f23.y, ar3);
            m0 = fmaxf(m0, fmaxf(t0, 0.2f * t0));
            m1 = fmaxf(m1, fmaxf(t1, 0.2f * t1));
            m2 = fmaxf(m2, fmaxf(t2, 0.2f * t2));
            m3 = fmaxf(m3, fmaxf(t3, 0.2f * t3));
        }
        z0 = z1 = z2 = z3 = 0.f;
        a0 = a1 = a2 = a3 = 0.f;
        for (int e = beg; e < end; ++e) {
            int sA = esrc[e];
            uint2 hv = *(const uint2*)(hb + (((uint32_t)sA << 8) | cq8));
            float2 f01 = __half22float2(((const __half2*)&hv)[0]);
            float2 f23 = __half22float2(((const __half2*)&hv)[1]);
            float t0 = fmaf(al0, f01.x, ar0), t1 = fmaf(al1, f01.y, ar1);
            float t2 = fmaf(al2, f23.x, ar2), t3 = fmaf(al3, f23.y, ar3);
            float e0 = EXP2(fmaxf(t0, 0.2f * t0) - m0);
            float e1 = EXP2(fmaxf(t1, 0.2f * t1) - m1);
            float e2 = EXP2(fmaxf(t2, 0.2f * t2) - m2);
            float e3 = EXP2(fmaxf(t3, 0.2f * t3) - m3);
            z0 += e0; z1 += e1; z2 += e2; z3 += e3;
            a0 = fmaf(e0, f01.x, a0); a1 = fmaf(e1, f01.y, a1);
            a2 = fmaf(e2, f23.x, a2); a3 = fmaf(e3, f23.y, a3);
        }
    } else {
        // merge parity halves: plain adds (shared implicit reference)
        z0 += __shfl_xor(z0, 32, 64); z1 += __shfl_xor(z1, 32, 64);
        z2 += __shfl_xor(z2, 32, 64); z3 += __shfl_xor(z3, 32, 64);
        a0 += __shfl_xor(a0, 32, 64); a1 += __shfl_xor(a1, 32, 64);
        a2 += __shfl_xor(a2, 32, 64); a3 += __shfl_xor(a3, 32, 64);
    }

    if (half == 0) {
        float o0 = (z0 > 0.f) ? a0 / z0 : 0.f;
        float o1 = (z1 > 0.f) ? a1 / z1 : 0.f;
        float o2 = (z2 > 0.f) ? a2 / z2 : 0.f;
        float o3 = (z3 > 0.f) ? a3 / z3 : 0.f;
        o0 = fmaxf(o0, neg_out * o0);
        o1 = fmaxf(o1, neg_out * o1);
        o2 = fmaxf(o2, neg_out * o2);
        o3 = fmaxf(o3, neg_out * o3);
        union { _Float16 hh[4]; uint2 u; } cv;
        cv.hh[0] = (_Float16)o0; cv.hh[1] = (_Float16)o1;
        cv.hh[2] = (_Float16)o2; cv.hh[3] = (_Float16)o3;
        *(uint2*)&xout[(size_t)node * 128 + cq * 4] = cv.u;
    }
}

// ---------------- final linear via MFMA: y = x(fp16) @ Wct^T + bc ----------

__global__ __launch_bounds__(256) void k_lin64(const __half* __restrict__ xh,
                                               const __half* __restrict__ Wcht,
                                               const float* __restrict__ bc,
                                               float* __restrict__ y,
                                               __half* __restrict__ yh, int n) {
    __shared__ _Float16 wsh[64 * LSTR];    // 17KB: W fp16, then fp32 out staging
    __shared__ _Float16 xsh[64 * LSTR];    // 17KB: x fp16, then fp16 out
    int t = threadIdx.x;
    int node0 = blockIdx.x * 64;
    for (int i = t; i < 1024; i += 256) {  // W: 64 rows x 16 uint4 (128 fp16/row)
        int r = i >> 4, c16 = i & 15;
        *(uint4*)&wsh[r * LSTR + c16 * 8] = ((const uint4*)Wcht)[i];
    }
    for (int i = t; i < 1024; i += 256) {  // x: 64 rows x 16 uint4, straight copy
        int r = i >> 4, c8 = i & 15;
        int gn = node0 + r;
        uint4 v = (gn < n) ? ((const uint4*)xh)[(size_t)gn * 16 + c8]
                           : make_uint4(0u, 0u, 0u, 0u);
        *(uint4*)&xsh[r * LSTR + c8 * 8] = v;
    }
    __syncthreads();
    int w = t >> 6, l = t & 63;
    int lr = l & 15, lg = l >> 4;
    int nrow0 = w * 16;                    // node stripe base
    f32x4 acc0 = {0.f, 0.f, 0.f, 0.f};
    f32x4 acc1 = acc0, acc2 = acc0, acc3 = acc0;
    #pragma unroll
    for (int kk = 0; kk < 4; ++kk) {
        int ko = kk * 32 + lg * 8;
        f16x8 a  = *(const f16x8*)&xsh[(nrow0 + lr) * LSTR + ko];
        f16x8 b0 = *(const f16x8*)&wsh[( 0 + lr) * LSTR + ko];
        f16x8 b1 = *(const f16x8*)&wsh[(16 + lr) * LSTR + ko];
        f16x8 b2 = *(const f16x8*)&wsh[(32 + lr) * LSTR + ko];
        f16x8 b3 = *(const f16x8*)&wsh[(48 + lr) * LSTR + ko];
        acc0 = __builtin_amdgcn_mfma_f32_16x16x32_f16(a, b0, acc0, 0, 0, 0);
        acc1 = __builtin_amdgcn_mfma_f32_16x16x32_f16(a, b1, acc1, 0, 0, 0);
        acc2 = __builtin_amdgcn_mfma_f32_16x16x32_f16(a, b2, acc2, 0, 0, 0);
        acc3 = __builtin_amdgcn_mfma_f32_16x16x32_f16(a, b3, acc3, 0, 0, 0);
    }
    float b0v = bc[ 0 + lr], b1v = bc[16 + lr];
    float b2v = bc[32 + lr], b3v = bc[48 + lr];
    __syncthreads();                       // all LDS reads done
    float* osh = (float*)wsh;              // [64][68] fp32 = 17408B, fits wsh
    int orow = nrow0 + lg * 4;
    #pragma unroll
    for (int j = 0; j < 4; ++j) {
        float v0 = acc0[j] + b0v, v1 = acc1[j] + b1v;
        float v2 = acc2[j] + b2v, v3 = acc3[j] + b3v;
        osh[(orow + j) * 68 +  0 + lr] = v0;
        osh[(orow + j) * 68 + 16 + lr] = v1;
        osh[(orow + j) * 68 + 32 + lr] = v2;
        osh[(orow + j) * 68 + 48 + lr] = v3;
        xsh[(orow + j) * LSTR +  0 + lr] = (_Float16)v0;
        xsh[(orow + j) * LSTR + 16 + lr] = (_Float16)v1;
        xsh[(orow + j) * LSTR + 32 + lr] = (_Float16)v2;
        xsh[(orow + j) * LSTR + 48 + lr] = (_Float16)v3;
    }
    __syncthreads();
    for (int i = t; i < 1024; i += 256) {  // y fp32: 64 rows x 16 float4
        int r = i >> 4, c4 = i & 15;
        int gn = node0 + r;
        if (gn < n)
            ((float4*)&y[(size_t)gn * 64])[c4] = *(float4*)&osh[r * 68 + c4 * 4];
    }
    for (int i = t; i < 1024; i += 256) {  // yh fp16: 64 rows x 16 uint2 (4 fp16 each)
        int r = i >> 4, c4 = i & 15;
        int gn = node0 + r;
        if (gn < n)
            *(uint2*)&yh[(size_t)gn * 64 + c4 * 4] = *(uint2*)&xsh[r * LSTR + c4 * 4];
    }
}

// ---------------- edge scores: sigmoid(dot(x[src], x[dst])), fp16 gather, 8 lanes/edge ----------------

__global__ __launch_bounds__(256) void k_edge_score(const __half* __restrict__ xh,
                                                    const int* __restrict__ src,
                                                    const int* __restrict__ dst,
                                                    float* __restrict__ out, int e_cnt) {
    int t = blockIdx.x * 256 + threadIdx.x;
    int e = t >> 3;
    int l = t & 7;
    if (e >= e_cnt) return;
    int u = src[e], v = dst[e];
    uint4 ua = ((const uint4*)&xh[(size_t)u * 64])[l];
    uint4 vb = ((const uint4*)&xh[(size_t)v * 64])[l];
    const __half2* pa = (const __half2*)&ua;
    const __half2* pb = (const __half2*)&vb;
    float d = 0.f;
    #pragma unroll
    for (int j = 0; j < 4; ++j) {
        float2 fa = __half22float2(pa[j]);
        float2 fb = __half22float2(pb[j]);
        d = fmaf(fa.x, fb.x, d);
        d = fmaf(fa.y, fb.y, d);
    }
    d += __shfl_xor(d, 1);
    d += __shfl_xor(d, 2);
    d += __shfl_xor(d, 4);
    if (l == 0) out[e] = 1.f / (1.f + __expf(-d));
}

// ---------------- launch ----------------

extern "C" void kernel_launch(void* const* d_in, const int* in_sizes, int n_in,
                              void* d_out, int out_size, void* d_ws, size_t ws_size,
                              hipStream_t stream) {
    const float* emb   = (const float*)d_in[0];
    const int*   ei    = (const int*)d_in[1];
    const float* W0    = (const float*)d_in[2];
    const float* b0    = (const float*)d_in[3];
    const float* attl0 = (const float*)d_in[4];
    const float* attr0 = (const float*)d_in[5];
    const float* W1    = (const float*)d_in[6];
    const float* b1    = (const float*)d_in[7];
    const float* attl1 = (const float*)d_in[8];
    const float* attr1 = (const float*)d_in[9];
    const float* pW1   = (const float*)d_in[10];
    const float* pb1   = (const float*)d_in[11];
    const float* pW2   = (const float*)d_in[12];
    const float* pb2   = (const float*)d_in[13];

    const int* src = ei;
    const int* dst = ei + N_EDGES;

    float* out = (float*)d_out;          // [E]
    float* xo  = out + N_EDGES;          // [N,64] fp32 node output

    char* ws = (char*)d_ws;
    size_t o = 0;
    auto alloc = [&](size_t bytes) {
        char* p = ws + o;
        o = (o + bytes + 255) & ~(size_t)255;
        return p;
    };
    int*    off   = (int*)alloc((size_t)(N_NODES + 1) * 4);
    int*    esrc  = (int*)alloc((size_t)N_EDGES * 4);
    int*    bcnt  = (int*)alloc((size_t)(NBKT + 1) * 4);
    int*    bbase = (int*)alloc((size_t)(NBKT + 1) * 4);
    int*    bcur  = (int*)alloc((size_t)(NBKT + 1) * 4);
    uint2*  ebuf  = (uint2*)alloc((size_t)N_EDGES * 8);
    __half* hbuf  = (__half*)alloc((size_t)N_NODES * HC * 2);
    __half* xh    = (__half*)alloc((size_t)N_NODES * HC * 2);
    __half* yh    = (__half*)alloc((size_t)N_NODES * OUTD * 2);
    __half* Wh0   = (__half*)alloc((size_t)HC * HC * 2);
    __half* Wh1   = (__half*)alloc((size_t)HC * HC * 2);
    __half* Wcht  = (__half*)alloc((size_t)HC * OUTD * 2);
    float*  bc    = (float*)alloc((size_t)OUTD * 4);
    (void)ws_size; (void)in_sizes; (void)n_in; (void)out_size;

    const int L128_NB = (N_NODES + 31) / 32;       // 1563
    const int L64_NB  = (N_NODES + 63) / 64;       // 782
    const int PREP_NB = (HC * HC + HC * OUTD + OUTD + 1023) / 1024;  // 25

    // CSR histogram + fused weight prep
    hipMemsetAsync(bcnt, 0, (size_t)(NBKT + 1) * 4, stream);
    k_hist_prep<<<EB_NB + PREP_NB, 1024, 0, stream>>>(dst, bcnt, N_EDGES,
                                                      W0, W1, pW1, pb1, pW2, pb2,
                                                      Wh0, Wh1, Wcht, bc);
    k_bscan   <<<1, 1024, 0, stream>>>(bcnt, bbase, bcur);
    k_bscatter<<<EB_NB, 1024, 0, stream>>>(src, dst, bcur, ebuf, N_EDGES);
    k_bfinal  <<<NBKT, 256, 0, stream>>>(ebuf, bbase, off, esrc, N_NODES);

    // GAT layer 0
    k_lin128<false><<<L128_NB, 256, 0, stream>>>(emb, Wh0, b0, hbuf, N_NODES);
    k_gat_agg<<<(N_NODES + 3) / 4, 256, 0, stream>>>(hbuf, off, esrc, attl0, attr0,
                                                     xh, N_NODES, 0.01f);
    // GAT layer 1
    k_lin128<true><<<L128_NB, 256, 0, stream>>>(xh, Wh1, b1, hbuf, N_NODES);
    k_gat_agg<<<(N_NODES + 3) / 4, 256, 0, stream>>>(hbuf, off, esrc, attl1, attr1,
                                                     xh, N_NODES, 0.01f);

    // post_mp (combined) + node output (fp32 + fp16 copy)
    k_lin64<<<L64_NB, 256, 0, stream>>>(xh, Wcht, bc, xo, yh, N_NODES);

    // edge scores
    k_edge_score<<<(N_EDGES * 8 + 255) / 256, 256, 0, stream>>>(yh, src, dst, out, N_EDGES);
}

// Round 17
// 179.180 us; speedup vs baseline: 1.0466x; 1.0466x over previous
//
#include <hip/hip_runtime.h>
#include <hip/hip_bf16.h>
#include <hip/hip_fp16.h>
#include <math.h>

#define N_NODES 50000
#define N_EDGES 800000
#define HC      128     // HEADS*HID
#define OUTD    64
#define NBKT    ((N_NODES + 63) / 64)   // 782 buckets of 64 nodes

// fast exp2: single v_exp_f32
#if defined(__has_builtin)
#if __has_builtin(__builtin_amdgcn_exp2f)
#define EXP2(x) __builtin_amdgcn_exp2f(x)
#endif
#endif
#ifndef EXP2
#define EXP2(x) __expf((x) * 0.69314718055994531f)
#endif

typedef _Float16 f16x8 __attribute__((ext_vector_type(8)));
typedef float f32x4 __attribute__((ext_vector_type(4)));

// ---------------- bucketed CSR build (round 8: WRITE_SIZE 51.6->~10MB) ------

__global__ __launch_bounds__(1024) void k_hist(const int* __restrict__ dst,
                                               int* __restrict__ bcnt, int e_cnt) {
    __shared__ int lh[NBKT];
    for (int i = threadIdx.x; i < NBKT; i += 1024) lh[i] = 0;
    __syncthreads();
    int base = blockIdx.x * 8192;
    for (int i = threadIdx.x; i < 8192; i += 1024) {
        int e = base + i;
        if (e < e_cnt) atomicAdd(&lh[dst[e] >> 6], 1);
    }
    __syncthreads();
    for (int i = threadIdx.x; i < NBKT; i += 1024) {
        int c = lh[i];
        if (c) atomicAdd(&bcnt[i], c);
    }
}

__global__ __launch_bounds__(1024) void k_bscan(const int* __restrict__ bcnt,
                                                int* __restrict__ bbase,
                                                int* __restrict__ bcur) {
    __shared__ int wsum[16];
    __shared__ int wexc[16];
    int t = threadIdx.x, lane = t & 63, wid = t >> 6;
    int v = (t < NBKT) ? bcnt[t] : 0;
    int incl = v;
    #pragma unroll
    for (int s = 1; s < 64; s <<= 1) {
        int u = __shfl_up(incl, s, 64);
        if (lane >= s) incl += u;
    }
    if (lane == 63) wsum[wid] = incl;
    __syncthreads();
    if (wid == 0 && lane < 16) {
        int w = wsum[lane];
        int wi = w;
        #pragma unroll
        for (int s = 1; s < 16; s <<= 1) {
            int u = __shfl_up(wi, s, 64);
            if (lane >= s) wi += u;
        }
        wexc[lane] = wi - w;
    }
    __syncthreads();
    int ex = wexc[wid] + incl - v;
    if (t < NBKT) { bbase[t] = ex; bcur[t] = ex; }
    if (t == NBKT - 1) bbase[NBKT] = ex + v;   // == e_cnt
}

__global__ __launch_bounds__(1024) void k_bscatter(const int* __restrict__ src,
                                                   const int* __restrict__ dst,
                                                   int* __restrict__ bcur,
                                                   uint2* __restrict__ ebuf, int e_cnt) {
    __shared__ int lcnt[NBKT];
    __shared__ int lbase[NBKT];
    for (int i = threadIdx.x; i < NBKT; i += 1024) lcnt[i] = 0;
    __syncthreads();
    int base = blockIdx.x * 8192;
    int myS[8], myD[8], myR[8];
    #pragma unroll
    for (int j = 0; j < 8; ++j) {
        int e = base + threadIdx.x + j * 1024;          // coalesced
        if (e < e_cnt) {
            myS[j] = src[e];
            myD[j] = dst[e];
            myR[j] = atomicAdd(&lcnt[myD[j] >> 6], 1);  // LDS rank (fast)
        } else myD[j] = -1;
    }
    __syncthreads();
    for (int i = threadIdx.x; i < NBKT; i += 1024) {
        int c = lcnt[i];
        lbase[i] = c ? atomicAdd(&bcur[i], c) : 0;      // reserve range once
    }
    __syncthreads();
    #pragma unroll
    for (int j = 0; j < 8; ++j) {
        if (myD[j] >= 0) {
            int bkt = myD[j] >> 6;
            ebuf[lbase[bkt] + myR[j]] =
                make_uint2((unsigned)myS[j], (unsigned)myD[j]);
        }
    }
}

__global__ __launch_bounds__(256) void k_bfinal(const uint2* __restrict__ ebuf,
                                                const int* __restrict__ bbase,
                                                int* __restrict__ off,
                                                int* __restrict__ esrc, int n) {
    __shared__ int ncnt[64];
    __shared__ int ncur[64];
    int b = blockIdx.x;
    int t = threadIdx.x;
    int ebeg = bbase[b], eend = bbase[b + 1];
    if (t < 64) ncnt[t] = 0;
    __syncthreads();
    for (int e = ebeg + t; e < eend; e += 256)
        atomicAdd(&ncnt[ebuf[e].y & 63], 1);
    __syncthreads();
    if (t < 64) {
        int v = ncnt[t];
        int incl = v;
        #pragma unroll
        for (int s = 1; s < 64; s <<= 1) {
            int u = __shfl_up(incl, s, 64);
            if (t >= s) incl += u;
        }
        int ex = incl - v;
        ncur[t] = ex;
        int node = b * 64 + t;
        if (node <= n) off[node] = ebeg + ex;   // covers off[n] via last bucket
    }
    __syncthreads();
    for (int e = ebeg + t; e < eend; e += 256) {
        uint2 ed = ebuf[e];
        int r = atomicAdd(&ncur[ed.y & 63], 1);
        esrc[ebeg + r] = (int)ed.x;             // contiguous 4KB region per block
    }
}

// ---------------- weight prep: fp16 W0/W1 + fp16-transposed post_mp combine --

__global__ void k_prep(const float* __restrict__ W0, const float* __restrict__ W1,
                       const float* __restrict__ pW1, const float* __restrict__ pb1,
                       const float* __restrict__ pW2, const float* __restrict__ pb2,
                       __half* __restrict__ Wh0, __half* __restrict__ Wh1,
                       __half* __restrict__ Wcht, float* __restrict__ bc) {
    int i = blockIdx.x * blockDim.x + threadIdx.x;
    if (i < HC * HC) {
        Wh0[i] = __float2half(W0[i]);
        Wh1[i] = __float2half(W1[i]);
    } else if (i < HC * HC + HC * OUTD) {
        int j = i - HC * HC;
        int k = j >> 6, o2 = j & 63;
        float s = 0.f;
        for (int m = 0; m < 64; ++m) s += pW2[o2 * 64 + m] * pW1[m * 128 + k];
        Wcht[o2 * 128 + k] = __float2half(s);   // [out][k] rows for MFMA B
    } else if (i < HC * HC + HC * OUTD + OUTD) {
        int o2 = i - HC * HC - HC * OUTD;
        float s = pb2[o2];
        for (int m = 0; m < 64; ++m) s += pW2[o2 * 64 + m] * pb1[m];
        bc[o2] = s;
    }
}

// ---------------- linear via MFMA: h = x @ W^T + b (round 11, verified) ------

#define LSTR 136   // padded LDS row stride in fp16 elems

__global__ __launch_bounds__(256) void k_lin128(const float* __restrict__ x,
                                                const __half* __restrict__ Wh,
                                                const float* __restrict__ bias,
                                                __half* __restrict__ h, int n) {
    __shared__ _Float16 wsh[128 * LSTR];   // 34.0KB: W fp16, padded rows
    __shared__ _Float16 xsh[32 * LSTR];    // 8.5KB: x fp16 (reused for output)
    int t = threadIdx.x;
    int node0 = blockIdx.x * 32;
    for (int i = t; i < 2048; i += 256) {
        int r = i >> 4, c16 = i & 15;
        *(uint4*)&wsh[r * LSTR + c16 * 8] = ((const uint4*)Wh)[i];
    }
    for (int i = t; i < 1024; i += 256) {
        int r = i >> 5, c4 = i & 31;
        int gn = node0 + r;
        float4 v = (gn < n) ? ((const float4*)x)[(size_t)gn * 32 + c4]
                            : make_float4(0.f, 0.f, 0.f, 0.f);
        union { _Float16 hh[4]; uint2 u; } cv;
        cv.hh[0] = (_Float16)v.x; cv.hh[1] = (_Float16)v.y;
        cv.hh[2] = (_Float16)v.z; cv.hh[3] = (_Float16)v.w;
        *(uint2*)&xsh[r * LSTR + c4 * 4] = cv.u;
    }
    __syncthreads();
    int w = t >> 6, l = t & 63;
    int lr = l & 15, lg = l >> 4;          // row-in-tile, k-group
    int nrow0 = (w >> 1) * 16;             // node tile base (0 / 16)
    int ccol0 = (w & 1) * 64;              // ch tile base (0 / 64)
    f32x4 acc0 = {0.f, 0.f, 0.f, 0.f};
    f32x4 acc1 = acc0, acc2 = acc0, acc3 = acc0;
    #pragma unroll
    for (int kk = 0; kk < 4; ++kk) {
        int ko = kk * 32 + lg * 8;
        f16x8 a  = *(const f16x8*)&xsh[(nrow0 + lr) * LSTR + ko];
        f16x8 b0 = *(const f16x8*)&wsh[(ccol0 +  0 + lr) * LSTR + ko];
        f16x8 b1 = *(const f16x8*)&wsh[(ccol0 + 16 + lr) * LSTR + ko];
        f16x8 b2 = *(const f16x8*)&wsh[(ccol0 + 32 + lr) * LSTR + ko];
        f16x8 b3 = *(const f16x8*)&wsh[(ccol0 + 48 + lr) * LSTR + ko];
        acc0 = __builtin_amdgcn_mfma_f32_16x16x32_f16(a, b0, acc0, 0, 0, 0);
        acc1 = __builtin_amdgcn_mfma_f32_16x16x32_f16(a, b1, acc1, 0, 0, 0);
        acc2 = __builtin_amdgcn_mfma_f32_16x16x32_f16(a, b2, acc2, 0, 0, 0);
        acc3 = __builtin_amdgcn_mfma_f32_16x16x32_f16(a, b3, acc3, 0, 0, 0);
    }
    float b0v = bias[ccol0 +  0 + lr];
    float b1v = bias[ccol0 + 16 + lr];
    float b2v = bias[ccol0 + 32 + lr];
    float b3v = bias[ccol0 + 48 + lr];
    __syncthreads();                       // all xsh reads done before overwrite
    int orow = nrow0 + lg * 4;
    #pragma unroll
    for (int j = 0; j < 4; ++j) {
        xsh[(orow + j) * LSTR + ccol0 +  0 + lr] = (_Float16)(acc0[j] + b0v);
        xsh[(orow + j) * LSTR + ccol0 + 16 + lr] = (_Float16)(acc1[j] + b1v);
        xsh[(orow + j) * LSTR + ccol0 + 32 + lr] = (_Float16)(acc2[j] + b2v);
        xsh[(orow + j) * LSTR + ccol0 + 48 + lr] = (_Float16)(acc3[j] + b3v);
    }
    __syncthreads();
    for (int i = t; i < 1024; i += 256) {
        int r = i >> 5, c4 = i & 31;
        int gn = node0 + r;
        if (gn < n)
            *(uint2*)&h[(size_t)gn * 128 + c4 * 4] = *(uint2*)&xsh[r * LSTR + c4 * 4];
    }
}

// ---------------- GAT aggregate (round 9/10 2-way version, 47us verified) ----
// One wave per dst node, two half-waves by edge parity. Max-free log2-domain
// softmax (scores O(+-5); safety fallback below). Direct broadcast esrc loads
// (half-wave-uniform -> one L1 transaction, 64B line = 8 steps of reuse).
// Rounds 14 (4-way) and 16 (fp16 out) both regressed via VGPR/occupancy;
// this VGPR-32 form is the measured local optimum.

__global__ __launch_bounds__(256) void k_gat_agg(const __half* __restrict__ h,
                                                 const int* __restrict__ off,
                                                 const int* __restrict__ esrc,
                                                 const float* __restrict__ attl,
                                                 const float* __restrict__ attr,
                                                 float* __restrict__ xout, int n,
                                                 float neg_out) {
    const float L2E = 1.4426950408889634f;
    int wid  = threadIdx.x >> 6;
    int lane = threadIdx.x & 63;
    int node = blockIdx.x * 4 + wid;
    if (node >= n) return;
    int half = lane >> 5;               // edge parity this half-wave owns
    int cq   = lane & 31;               // channel quad index
    uint32_t cq8 = (uint32_t)cq << 3;   // byte offset of my 4 fp16 channels

    const char* hb = (const char*)h;    // uniform base (SGPR) -- saddr form

    float4 alv = ((const float4*)attl)[cq];
    float4 arv = ((const float4*)attr)[cq];
    uint2 hdr = *(const uint2*)(hb + ((((uint32_t)node << 8)) | cq8));
    float2 hd01 = __half22float2(((const __half2*)&hdr)[0]);
    float2 hd23 = __half22float2(((const __half2*)&hdr)[1]);
    float al0 = alv.x * L2E, al1 = alv.y * L2E;
    float al2 = alv.z * L2E, al3 = alv.w * L2E;
    float ar0 = arv.x * hd01.x * L2E, ar1 = arv.y * hd01.y * L2E;
    float ar2 = arv.z * hd23.x * L2E, ar3 = arv.w * hd23.y * L2E;

    float z0 = 0.f, z1 = 0.f, z2 = 0.f, z3 = 0.f;
    float a0 = 0.f, a1 = 0.f, a2 = 0.f, a3 = 0.f;

    int beg = off[node], end = off[node + 1];

#define STEP(sAv)                                                              \
    {   uint32_t voff = (((uint32_t)(sAv)) << 8) | cq8;                        \
        uint2 hv = *(const uint2*)(hb + voff);                                 \
        float2 f01 = __half22float2(((const __half2*)&hv)[0]);                 \
        float2 f23 = __half22float2(((const __half2*)&hv)[1]);                 \
        float t0 = fmaf(al0, f01.x, ar0), t1 = fmaf(al1, f01.y, ar1);          \
        float t2 = fmaf(al2, f23.x, ar2), t3 = fmaf(al3, f23.y, ar3);          \
        float e0 = EXP2(fmaxf(t0, 0.2f * t0)), e1 = EXP2(fmaxf(t1, 0.2f * t1));\
        float e2 = EXP2(fmaxf(t2, 0.2f * t2)), e3 = EXP2(fmaxf(t3, 0.2f * t3));\
        z0 += e0; z1 += e1; z2 += e2; z3 += e3;                                \
        a0 = fmaf(e0, f01.x, a0); a1 = fmaf(e1, f01.y, a1);                    \
        a2 = fmaf(e2, f23.x, a2); a3 = fmaf(e3, f23.y, a3);                    \
    }

    {
        int e = beg;
        #pragma unroll 4
        for (; e + 2 <= end; e += 2) {
            int sA = esrc[e + half];    // half-wave-uniform -> L1 broadcast
            STEP(sA);
        }
        if (e < end) {                  // one leftover edge (even parity)
            int sA = esrc[end - 1];
            if (half == 0) STEP(sA);
        }
    }
#undef STEP

    // validity: overflow -> z inf/NaN; total underflow -> z==0 with edges
    float zs = z0 + z1 + z2 + z3;
    bool bad = !(zs < 3.0e38f);
    if (beg < end)
        bad = bad || !((z0 > 0.f) && (z1 > 0.f) && (z2 > 0.f) && (z3 > 0.f));

    if (__any(bad)) {
        // slow safe path (~never): two-pass max-shifted softmax; every lane
        // walks ALL edges, so both halves hold identical full sums (no merge).
        float m0 = -1e30f, m1 = -1e30f, m2 = -1e30f, m3 = -1e30f;
        for (int e = beg; e < end; ++e) {
            int sA = esrc[e];
            uint2 hv = *(const uint2*)(hb + (((uint32_t)sA << 8) | cq8));
            float2 f01 = __half22float2(((const __half2*)&hv)[0]);
            float2 f23 = __half22float2(((const __half2*)&hv)[1]);
            float t0 = fmaf(al0, f01.x, ar0), t1 = fmaf(al1, f01.y, ar1);
            float t2 = fmaf(al2, f23.x, ar2), t3 = fmaf(al3, f23.y, ar3);
            m0 = fmaxf(m0, fmaxf(t0, 0.2f * t0));
            m1 = fmaxf(m1, fmaxf(t1, 0.2f * t1));
            m2 = fmaxf(m2, fmaxf(t2, 0.2f * t2));
            m3 = fmaxf(m3, fmaxf(t3, 0.2f * t3));
        }
        z0 = z1 = z2 = z3 = 0.f;
        a0 = a1 = a2 = a3 = 0.f;
        for (int e = beg; e < end; ++e) {
            int sA = esrc[e];
            uint2 hv = *(const uint2*)(hb + (((uint32_t)sA << 8) | cq8));
            float2 f01 = __half22float2(((const __half2*)&hv)[0]);
            float2 f23 = __half22float2(((const __half2*)&hv)[1]);
            float t0 = fmaf(al0, f01.x, ar0), t1 = fmaf(al1, f01.y, ar1);
            float t2 = fmaf(al2, f23.x, ar2), t3 = fmaf(al3, f23.y, ar3);
            float e0 = EXP2(fmaxf(t0, 0.2f * t0) - m0);
            float e1 = EXP2(fmaxf(t1, 0.2f * t1) - m1);
            float e2 = EXP2(fmaxf(t2, 0.2f * t2) - m2);
            float e3 = EXP2(fmaxf(t3, 0.2f * t3) - m3);
            z0 += e0; z1 += e1; z2 += e2; z3 += e3;
            a0 = fmaf(e0, f01.x, a0); a1 = fmaf(e1, f01.y, a1);
            a2 = fmaf(e2, f23.x, a2); a3 = fmaf(e3, f23.y, a3);
        }
    } else {
        // merge parity halves: plain adds (shared implicit reference)
        z0 += __shfl_xor(z0, 32, 64); z1 += __shfl_xor(z1, 32, 64);
        z2 += __shfl_xor(z2, 32, 64); z3 += __shfl_xor(z3, 32, 64);
        a0 += __shfl_xor(a0, 32, 64); a1 += __shfl_xor(a1, 32, 64);
        a2 += __shfl_xor(a2, 32, 64); a3 += __shfl_xor(a3, 32, 64);
    }

    if (half == 0) {
        float o0 = (z0 > 0.f) ? a0 / z0 : 0.f;
        float o1 = (z1 > 0.f) ? a1 / z1 : 0.f;
        float o2 = (z2 > 0.f) ? a2 / z2 : 0.f;
        float o3 = (z3 > 0.f) ? a3 / z3 : 0.f;
        o0 = fmaxf(o0, neg_out * o0);
        o1 = fmaxf(o1, neg_out * o1);
        o2 = fmaxf(o2, neg_out * o2);
        o3 = fmaxf(o3, neg_out * o3);
        *(float4*)&xout[(size_t)node * 128 + cq * 4] = make_float4(o0, o1, o2, o3);
    }
}

// ---------------- final linear via MFMA: y = x @ Wct^T + bc, 64 out ----------
// (round 14, verified: full W staging + full yh copy)

__global__ __launch_bounds__(256) void k_lin64(const float* __restrict__ x,
                                               const __half* __restrict__ Wcht,
                                               const float* __restrict__ bc,
                                               float* __restrict__ y,
                                               __half* __restrict__ yh, int n) {
    __shared__ _Float16 wsh[64 * LSTR];    // 17KB: W fp16, then fp32 out staging
    __shared__ _Float16 xsh[64 * LSTR];    // 17KB: x fp16, then fp16 out
    int t = threadIdx.x;
    int node0 = blockIdx.x * 64;
    for (int i = t; i < 1024; i += 256) {  // 64 rows x 16 uint4 (128 fp16/row)
        int r = i >> 4, c16 = i & 15;
        *(uint4*)&wsh[r * LSTR + c16 * 8] = ((const uint4*)Wcht)[i];
    }
    for (int i = t; i < 2048; i += 256) {
        int r = i >> 5, c4 = i & 31;
        int gn = node0 + r;
        float4 v = (gn < n) ? ((const float4*)x)[(size_t)gn * 32 + c4]
                            : make_float4(0.f, 0.f, 0.f, 0.f);
        union { _Float16 hh[4]; uint2 u; } cv;
        cv.hh[0] = (_Float16)v.x; cv.hh[1] = (_Float16)v.y;
        cv.hh[2] = (_Float16)v.z; cv.hh[3] = (_Float16)v.w;
        *(uint2*)&xsh[r * LSTR + c4 * 4] = cv.u;
    }
    __syncthreads();
    int w = t >> 6, l = t & 63;
    int lr = l & 15, lg = l >> 4;
    int nrow0 = w * 16;                    // node stripe base
    f32x4 acc0 = {0.f, 0.f, 0.f, 0.f};
    f32x4 acc1 = acc0, acc2 = acc0, acc3 = acc0;
    #pragma unroll
    for (int kk = 0; kk < 4; ++kk) {
        int ko = kk * 32 + lg * 8;
        f16x8 a  = *(const f16x8*)&xsh[(nrow0 + lr) * LSTR + ko];
        f16x8 b0 = *(const f16x8*)&wsh[( 0 + lr) * LSTR + ko];
        f16x8 b1 = *(const f16x8*)&wsh[(16 + lr) * LSTR + ko];
        f16x8 b2 = *(const f16x8*)&wsh[(32 + lr) * LSTR + ko];
        f16x8 b3 = *(const f16x8*)&wsh[(48 + lr) * LSTR + ko];
        acc0 = __builtin_amdgcn_mfma_f32_16x16x32_f16(a, b0, acc0, 0, 0, 0);
        acc1 = __builtin_amdgcn_mfma_f32_16x16x32_f16(a, b1, acc1, 0, 0, 0);
        acc2 = __builtin_amdgcn_mfma_f32_16x16x32_f16(a, b2, acc2, 0, 0, 0);
        acc3 = __builtin_amdgcn_mfma_f32_16x16x32_f16(a, b3, acc3, 0, 0, 0);
    }
    float b0v = bc[ 0 + lr], b1v = bc[16 + lr];
    float b2v = bc[32 + lr], b3v = bc[48 + lr];
    __syncthreads();                       // all LDS reads done
    float* osh = (float*)wsh;              // [64][68] fp32 = 17408B, fits wsh
    int orow = nrow0 + lg * 4;
    #pragma unroll
    for (int j = 0; j < 4; ++j) {
        float v0 = acc0[j] + b0v, v1 = acc1[j] + b1v;
        float v2 = acc2[j] + b2v, v3 = acc3[j] + b3v;
        osh[(orow + j) * 68 +  0 + lr] = v0;
        osh[(orow + j) * 68 + 16 + lr] = v1;
        osh[(orow + j) * 68 + 32 + lr] = v2;
        osh[(orow + j) * 68 + 48 + lr] = v3;
        xsh[(orow + j) * LSTR +  0 + lr] = (_Float16)v0;
        xsh[(orow + j) * LSTR + 16 + lr] = (_Float16)v1;
        xsh[(orow + j) * LSTR + 32 + lr] = (_Float16)v2;
        xsh[(orow + j) * LSTR + 48 + lr] = (_Float16)v3;
    }
    __syncthreads();
    for (int i = t; i < 1024; i += 256) {  // y fp32: 64 rows x 16 float4
        int r = i >> 4, c4 = i & 15;
        int gn = node0 + r;
        if (gn < n)
            ((float4*)&y[(size_t)gn * 64])[c4] = *(float4*)&osh[r * 68 + c4 * 4];
    }
    for (int i = t; i < 1024; i += 256) {  // yh fp16: 64 rows x 16 uint2 (4 fp16 each)
        int r = i >> 4, c4 = i & 15;
        int gn = node0 + r;
        if (gn < n)
            *(uint2*)&yh[(size_t)gn * 64 + c4 * 4] = *(uint2*)&xsh[r * LSTR + c4 * 4];
    }
}

// ---------------- edge scores: sigmoid(dot(x[src], x[dst])), fp16 gather, 8 lanes/edge ----------------

__global__ __launch_bounds__(256) void k_edge_score(const __half* __restrict__ xh,
                                                    const int* __restrict__ src,
                                                    const int* __restrict__ dst,
                                                    float* __restrict__ out, int e_cnt) {
    int t = blockIdx.x * 256 + threadIdx.x;
    int e = t >> 3;
    int l = t & 7;
    if (e >= e_cnt) return;
    int u = src[e], v = dst[e];
    uint4 ua = ((const uint4*)&xh[(size_t)u * 64])[l];
    uint4 vb = ((const uint4*)&xh[(size_t)v * 64])[l];
    const __half2* pa = (const __half2*)&ua;
    const __half2* pb = (const __half2*)&vb;
    float d = 0.f;
    #pragma unroll
    for (int j = 0; j < 4; ++j) {
        float2 fa = __half22float2(pa[j]);
        float2 fb = __half22float2(pb[j]);
        d = fmaf(fa.x, fb.x, d);
        d = fmaf(fa.y, fb.y, d);
    }
    d += __shfl_xor(d, 1);
    d += __shfl_xor(d, 2);
    d += __shfl_xor(d, 4);
    if (l == 0) out[e] = 1.f / (1.f + __expf(-d));
}

// ---------------- launch ----------------

extern "C" void kernel_launch(void* const* d_in, const int* in_sizes, int n_in,
                              void* d_out, int out_size, void* d_ws, size_t ws_size,
                              hipStream_t stream) {
    const float* emb   = (const float*)d_in[0];
    const int*   ei    = (const int*)d_in[1];
    const float* W0    = (const float*)d_in[2];
    const float* b0    = (const float*)d_in[3];
    const float* attl0 = (const float*)d_in[4];
    const float* attr0 = (const float*)d_in[5];
    const float* W1    = (const float*)d_in[6];
    const float* b1    = (const float*)d_in[7];
    const float* attl1 = (const float*)d_in[8];
    const float* attr1 = (const float*)d_in[9];
    const float* pW1   = (const float*)d_in[10];
    const float* pb1   = (const float*)d_in[11];
    const float* pW2   = (const float*)d_in[12];
    const float* pb2   = (const float*)d_in[13];

    const int* src = ei;
    const int* dst = ei + N_EDGES;

    float* out = (float*)d_out;          // [E]
    float* xo  = out + N_EDGES;          // [N,64] fp32 node output

    char* ws = (char*)d_ws;
    size_t o = 0;
    auto alloc = [&](size_t bytes) {
        char* p = ws + o;
        o = (o + bytes + 255) & ~(size_t)255;
        return p;
    };
    int*    off   = (int*)alloc((size_t)(N_NODES + 1) * 4);
    int*    esrc  = (int*)alloc((size_t)N_EDGES * 4);
    int*    bcnt  = (int*)alloc((size_t)(NBKT + 1) * 4);
    int*    bbase = (int*)alloc((size_t)(NBKT + 1) * 4);
    int*    bcur  = (int*)alloc((size_t)(NBKT + 1) * 4);
    uint2*  ebuf  = (uint2*)alloc((size_t)N_EDGES * 8);
    __half* hbuf  = (__half*)alloc((size_t)N_NODES * HC * 2);
    float*  xbuf  = (float*)alloc((size_t)N_NODES * HC * 4);
    __half* yh    = (__half*)alloc((size_t)N_NODES * OUTD * 2);
    __half* Wh0   = (__half*)alloc((size_t)HC * HC * 2);
    __half* Wh1   = (__half*)alloc((size_t)HC * HC * 2);
    __half* Wcht  = (__half*)alloc((size_t)HC * OUTD * 2);
    float*  bc    = (float*)alloc((size_t)OUTD * 4);
    (void)ws_size; (void)in_sizes; (void)n_in; (void)out_size;

    const int L128_NB = (N_NODES + 31) / 32;       // 1563
    const int L64_NB  = (N_NODES + 63) / 64;       // 782
    const int EB_NB   = (N_EDGES + 8191) / 8192;   // 98
    const int PREP_N  = HC * HC + HC * OUTD + OUTD;

    // weight prep (independent of everything else)
    k_prep<<<(PREP_N + 255) / 256, 256, 0, stream>>>(W0, W1, pW1, pb1, pW2, pb2,
                                                     Wh0, Wh1, Wcht, bc);

    // bucketed CSR build
    hipMemsetAsync(bcnt, 0, (size_t)(NBKT + 1) * 4, stream);
    k_hist    <<<EB_NB, 1024, 0, stream>>>(dst, bcnt, N_EDGES);
    k_bscan   <<<1, 1024, 0, stream>>>(bcnt, bbase, bcur);
    k_bscatter<<<EB_NB, 1024, 0, stream>>>(src, dst, bcur, ebuf, N_EDGES);
    k_bfinal  <<<NBKT, 256, 0, stream>>>(ebuf, bbase, off, esrc, N_NODES);

    // GAT layer 0
    k_lin128<<<L128_NB, 256, 0, stream>>>(emb, Wh0, b0, hbuf, N_NODES);
    k_gat_agg<<<(N_NODES + 3) / 4, 256, 0, stream>>>(hbuf, off, esrc, attl0, attr0,
                                                     xbuf, N_NODES, 0.01f);
    // GAT layer 1
    k_lin128<<<L128_NB, 256, 0, stream>>>(xbuf, Wh1, b1, hbuf, N_NODES);
    k_gat_agg<<<(N_NODES + 3) / 4, 256, 0, stream>>>(hbuf, off, esrc, attl1, attr1,
                                                     xbuf, N_NODES, 0.01f);

    // post_mp (combined) + node output (fp32 + fp16 copy)
    k_lin64<<<L64_NB, 256, 0, stream>>>(xbuf, Wcht, bc, xo, yh, N_NODES);

    // edge scores
    k_edge_score<<<(N_EDGES * 8 + 255) / 256, 256, 0, stream>>>(yh, src, dst, out, N_EDGES);
}